// Round 15
// baseline (34.845 us; speedup 1.0000x reference)
//
#include <hip/hip_runtime.h>

#define INP (128*128*64)   // 1048576
#define NB 8
#define NBLK2 2048         // k_sample blocks per batch: (INP/2)/256

typedef __attribute__((ext_vector_type(4))) float f32x4;
typedef __attribute__((ext_vector_type(2))) float f32x2;
typedef __attribute__((ext_vector_type(2))) unsigned int u32x2;
typedef int v4i __attribute__((ext_vector_type(4)));

#if __has_builtin(__builtin_amdgcn_make_buffer_rsrc) && __has_builtin(__builtin_amdgcn_raw_buffer_load_b32)
#define RSRC_T __amdgpu_buffer_rsrc_t
__device__ __forceinline__ RSRC_T make_rsrc(const void* p, int bytes) {
    return __builtin_amdgcn_make_buffer_rsrc((void*)p, (short)0, bytes, 0x00020000);
}
__device__ __forceinline__ float bload(RSRC_T r, int boff) {
    return __builtin_bit_cast(float, __builtin_amdgcn_raw_buffer_load_b32(r, boff, 0, 0));
}
#else
#define RSRC_T v4i
__device__ __forceinline__ RSRC_T make_rsrc(const void* p, int bytes) {
    union { const void* p; unsigned u[2]; } pun; pun.p = p;
    RSRC_T r;
    r.x = (int)pun.u[0]; r.y = (int)pun.u[1]; r.z = bytes; r.w = 0x00020000;
    return r;
}
__device__ __forceinline__ float bload(RSRC_T r, int boff) {
    return __builtin_amdgcn_raw_buffer_load_f32(r, boff, 0, 0);
}
#endif

#if __has_builtin(__builtin_amdgcn_raw_buffer_load_b64)
__device__ __forceinline__ f32x2 bload2(RSRC_T r, int boff) {
    return __builtin_bit_cast(f32x2, __builtin_amdgcn_raw_buffer_load_b64(r, boff, 0, 0));
}
#else
__device__ __forceinline__ f32x2 bload2(RSRC_T r, int boff) {
    f32x2 v; v.x = bload(r, boff); v.y = bload(r, boff + 4); return v;
}
#endif

#if __has_builtin(__builtin_amdgcn_raw_buffer_store_b64)
#define HAVE_BSTORE2 1
__device__ __forceinline__ void bstore2(f32x2 v, RSRC_T r, int boff) {
    __builtin_amdgcn_raw_buffer_store_b64(__builtin_bit_cast(u32x2, v), r, boff, 0, 0);
}
#endif

__device__ __forceinline__ float wave_reduce(float v) {
    #pragma unroll
    for (int off = 32; off > 0; off >>= 1) v += __shfl_down(v, off, 64);
    return v;
}

// Per-sample prep state: 4 row-base byte offsets + 6 final weights.
// x-edges resolved in the weights (R13-proven):
//   interior: (wa,wb)=(wx0,wx1); x0=63: (0,wx0); x0=-1: (wx1,0); else (0,0).
struct Prep {
    int o[4];
    float wa, wb, wy0, wy1, wz0, wz1;
};

// SLOW path (boundary waves, ~12%): R12/R13-proven full clamp+zero prep.
// All offsets in-bounds by construction (R3/R7: never pair a possibly
// negative SRSRC voffset with a folded imm).
__device__ __forceinline__ Prep prep_s(float ix, float iy, float iz) {
    const float fx = floorf(ix), fy = floorf(iy), fz = floorf(iz);
    const int x0 = (int)fx, y0 = (int)fy, z0 = (int)fz;
    const int x1 = x0 + 1,  y1 = y0 + 1,  z1 = z0 + 1;

    const float wx1 = ix - fx, wx0 = 1.f - wx1;
    Prep p;
    p.wy1 = iy - fy; p.wy0 = 1.f - p.wy1;
    p.wz1 = iz - fz; p.wz0 = 1.f - p.wz1;
    p.wy0 = ((unsigned)y0 < 128u) ? p.wy0 : 0.f;
    p.wy1 = ((unsigned)y1 < 128u) ? p.wy1 : 0.f;
    p.wz0 = ((unsigned)z0 < 128u) ? p.wz0 : 0.f;
    p.wz1 = ((unsigned)z1 < 128u) ? p.wz1 : 0.f;

    const float wx0z = ((unsigned)x0 < 64u) ? wx0 : 0.f;
    const float wx1z = ((unsigned)x1 < 64u) ? wx1 : 0.f;
    const bool hi = (x0 >= 63);
    const bool lo = (x0 < 0);
    p.wa = lo ? wx1z : (hi ? 0.f : wx0z);
    p.wb = hi ? wx0z : (lo ? 0.f : wx1z);

    const int yc0 = min(max(y0, 0), 127), yc1 = min(max(y1, 0), 127);
    const int zc0 = min(max(z0, 0), 127), zc1 = min(max(z1, 0), 127);
    const int xpb = min(max(x0, 0), 62) << 2;
    const int yb0 = (yc0 << 8) + xpb, yb1 = (yc1 << 8) + xpb;
    const int zb0 = zc0 << 15,        zb1 = zc1 << 15;
    p.o[0] = zb0 + yb0; p.o[1] = zb0 + yb1;
    p.o[2] = zb1 + yb0; p.o[3] = zb1 + yb1;
    return p;
}

// FAST path: wave-uniformly y0,z0 in [0,126] -> rows y0,y0+1,z0,z0+1 all
// valid: no y/z zeroing, no clamps, one row base rb>=0 with folded-imm
// offsets (+256/+32768/+33024 — safe, voffset non-negative).
// x-edge logic identical to slow path (every wave spans the full x-row).
__device__ __forceinline__ Prep prep_f(float ix, float iy, float fyf, int y0,
                                       float iz, float fzf, int z0) {
    Prep p;
    p.wy1 = iy - fyf; p.wy0 = 1.f - p.wy1;
    p.wz1 = iz - fzf; p.wz0 = 1.f - p.wz1;

    const float fx = floorf(ix);
    const int x0 = (int)fx;
    const float wx1 = ix - fx, wx0 = 1.f - wx1;
    const float wx0z = ((unsigned)x0 < 64u) ? wx0 : 0.f;
    const float wx1z = ((unsigned)(x0 + 1) < 64u) ? wx1 : 0.f;
    const bool hi = (x0 >= 63);
    const bool lo = (x0 < 0);
    p.wa = lo ? wx1z : (hi ? 0.f : wx0z);
    p.wb = hi ? wx0z : (lo ? 0.f : wx1z);

    const int rb = (z0 << 15) + (y0 << 8) + (min(max(x0, 0), 62) << 2);
    p.o[0] = rb;           p.o[1] = rb + 256;
    p.o[2] = rb + 32768;   p.o[3] = rb + 32768 + 256;
    return p;
}

__device__ __forceinline__ float blend_s(const Prep& p, const f32x2 v[4]) {
    const float bx00 = fmaf(p.wb, v[0].y, p.wa * v[0].x);
    const float bx01 = fmaf(p.wb, v[1].y, p.wa * v[1].x);
    const float bx10 = fmaf(p.wb, v[2].y, p.wa * v[2].x);
    const float bx11 = fmaf(p.wb, v[3].y, p.wa * v[3].x);
    const float by0  = fmaf(p.wy1, bx01, p.wy0 * bx00);
    const float by1  = fmaf(p.wy1, bx11, p.wy0 * bx10);
    return fmaf(p.wz1, by1, p.wz0 * by0);
}

// ---------------------------------------------------------------------------
// K1: one thread = TWO x-adjacent voxels (R12-proven); R13 2D grid (R14's
// batch-per-XCD swizzle regressed: FETCH 19.7->32.7MB, L2 thrash). Wave-
// uniform y/z interior check picks fast/slow prep. SRSRC lnw load + x_reg
// store (32-bit voffset, no 64-bit flat address arith).
// ---------------------------------------------------------------------------
__global__ __launch_bounds__(256) void k_sample(
    const float* __restrict__ x, const int* __restrict__ r_index,
    const float* __restrict__ theta, const float* __restrict__ lnw,
    float* __restrict__ x_reg, float* __restrict__ partial)
{
    const int b  = blockIdx.y;
    const int i2 = blockIdx.x * 256 + threadIdx.x;   // pair index
    const int w0 = (i2 & 31) << 1;                   // w of voxel 0
    const int h  = (i2 >> 5) & 127;
    const int d  = i2 >> 12;

    const RSRC_T rw = make_rsrc(lnw, INP * 4);
    const f32x2 w2 = bload2(rw, i2 << 3);            // issue early

    const float xs = fmaf((float)w0, 1.f/32.f, 1.f/64.f  - 1.f);
    const float ys = fmaf((float)h,  1.f/64.f, 1.f/128.f - 1.f);
    const float zs = fmaf((float)d,  1.f/64.f, 1.f/128.f - 1.f);

    const float* __restrict__ t = theta + r_index[b] * 12;   // uniform
    const float gx = fmaf(t[0], xs, fmaf(t[1], ys, fmaf(t[2],  zs, t[3])));
    const float gy = fmaf(t[4], xs, fmaf(t[5], ys, fmaf(t[6],  zs, t[7])));
    const float gz = fmaf(t[8], xs, fmaf(t[9], ys, fmaf(t[10], zs, t[11])));
    const float ix0 = fmaf(gx, 32.f, 31.5f);
    const float iy0 = fmaf(gy, 64.f, 63.5f);
    const float iz0 = fmaf(gz, 64.f, 63.5f);
    const float ix1 = ix0 + t[0];
    const float iy1 = iy0 + 2.f * t[4];
    const float iz1 = iz0 + 2.f * t[8];

    const float fy0f = floorf(iy0), fz0f = floorf(iz0);
    const float fy1f = floorf(iy1), fz1f = floorf(iz1);
    const int y00 = (int)fy0f, z00 = (int)fz0f;
    const int y10 = (int)fy1f, z10 = (int)fz1f;

    const int ok = ((unsigned)y00 <= 126u) & ((unsigned)z00 <= 126u) &
                   ((unsigned)y10 <= 126u) & ((unsigned)z10 <= 126u);

    Prep p0, p1;
    if (__all(ok)) {
        p0 = prep_f(ix0, iy0, fy0f, y00, iz0, fz0f, z00);
        p1 = prep_f(ix1, iy1, fy1f, y10, iz1, fz1f, z10);
    } else {
        p0 = prep_s(ix0, iy0, iz0);
        p1 = prep_s(ix1, iy1, iz1);
    }

    const RSRC_T r = make_rsrc(x + (size_t)b * INP, INP * 4);
    f32x2 v0[4], v1[4];
    #pragma unroll
    for (int j = 0; j < 4; ++j) v0[j] = bload2(r, p0.o[j]);
    #pragma unroll
    for (int j = 0; j < 4; ++j) v1[j] = bload2(r, p1.o[j]);

    const float o0 = blend_s(p0, v0);
    const float o1 = blend_s(p1, v1);

    f32x2 o; o.x = o0; o.y = o1;
#if defined(HAVE_BSTORE2)
    const RSRC_T rs = make_rsrc(x_reg + (size_t)b * INP, INP * 4);
    bstore2(o, rs, i2 << 3);
#else
    __builtin_nontemporal_store(o, (f32x2*)(x_reg + (size_t)b * INP) + i2);
#endif

    // R5-proven tail: wave shfl reduce -> LDS combine -> ONE store per block
    float acc = fmaf(o1, w2.y, o0 * w2.x);
    acc = wave_reduce(acc);
    __shared__ float sm[4];
    if ((threadIdx.x & 63) == 0) sm[threadIdx.x >> 6] = acc;
    __syncthreads();
    if (threadIdx.x == 0)
        partial[b * NBLK2 + blockIdx.x] = sm[0] + sm[1] + sm[2] + sm[3];
}

// ---------------------------------------------------------------------------
// K2 (fused reduce+outer, R13-proven): grid (128 chunks, 8 batches). Each
// block redundantly reduces its batch's 2048 partials then writes its
// 8192-float chunk of L[b] = s_b * lnw.
// ---------------------------------------------------------------------------
__global__ __launch_bounds__(256) void k_outer(
    const float* __restrict__ lnw, const float* __restrict__ partial,
    float* __restrict__ L)
{
    const int b   = blockIdx.y;
    const int tid = threadIdx.x;

    const f32x4* p4 = (const f32x4*)(partial + b * NBLK2);   // 512 f32x4
    const f32x4 a0 = p4[tid];
    const f32x4 a1 = p4[tid + 256];
    float v = (a0.x + a0.y) + (a0.z + a0.w) + (a1.x + a1.y) + (a1.z + a1.w);
    v = wave_reduce(v);
    __shared__ float sm[4];
    __shared__ float smt;
    if ((tid & 63) == 0) sm[tid >> 6] = v;
    __syncthreads();
    if (tid == 0) smt = (sm[0] + sm[1]) + (sm[2] + sm[3]);
    __syncthreads();
    const float sb = smt;

    const int base = blockIdx.x * 2048 + tid;    // f32x4 units within batch
    const f32x4* w4p = (const f32x4*)lnw;
    f32x4* L4 = (f32x4*)L + (size_t)b * (INP / 4);
    #pragma unroll
    for (int k = 0; k < 8; ++k) {
        const f32x4 w4 = w4p[base + k * 256];
        __builtin_nontemporal_store(sb * w4, L4 + base + k * 256);
    }
}

extern "C" void kernel_launch(void* const* d_in, const int* in_sizes, int n_in,
                              void* d_out, int out_size, void* d_ws, size_t ws_size,
                              hipStream_t stream) {
    const float* x       = (const float*)d_in[0];
    const int*   r_index = (const int*)d_in[1];
    const float* theta   = (const float*)d_in[2];
    const float* lnw     = (const float*)d_in[3];

    float* x_reg = (float*)d_out;
    float* L     = (float*)d_out + (size_t)NB * INP;

    float* partial = (float*)d_ws;            // 8*2048 floats = 64 KB

    dim3 grid1(NBLK2, NB);
    k_sample<<<grid1, 256, 0, stream>>>(x, r_index, theta, lnw, x_reg, partial);
    dim3 grid2(128, NB);
    k_outer<<<grid2, 256, 0, stream>>>(lnw, partial, L);
}

// Round 16
// 34.000 us; speedup vs baseline: 1.0248x; 1.0248x over previous
//
#include <hip/hip_runtime.h>

#define INP (128*128*64)   // 1048576
#define NB 8
#define NBLK2 2048         // k_sample blocks per batch: (INP/2)/256

typedef __attribute__((ext_vector_type(4))) float f32x4;
typedef __attribute__((ext_vector_type(2))) float f32x2;
typedef int v4i __attribute__((ext_vector_type(4)));

#if __has_builtin(__builtin_amdgcn_make_buffer_rsrc) && __has_builtin(__builtin_amdgcn_raw_buffer_load_b32)
#define RSRC_T __amdgpu_buffer_rsrc_t
__device__ __forceinline__ RSRC_T make_rsrc(const float* p) {
    return __builtin_amdgcn_make_buffer_rsrc((void*)p, (short)0, INP * 4, 0x00020000);
}
__device__ __forceinline__ float bload(RSRC_T r, int boff) {
    return __builtin_bit_cast(float, __builtin_amdgcn_raw_buffer_load_b32(r, boff, 0, 0));
}
#else
#define RSRC_T v4i
__device__ __forceinline__ RSRC_T make_rsrc(const float* p) {
    union { const float* p; unsigned u[2]; } pun; pun.p = p;
    RSRC_T r;
    r.x = (int)pun.u[0]; r.y = (int)pun.u[1]; r.z = INP * 4; r.w = 0x00020000;
    return r;
}
__device__ __forceinline__ float bload(RSRC_T r, int boff) {
    return __builtin_amdgcn_raw_buffer_load_f32(r, boff, 0, 0);
}
#endif

#if __has_builtin(__builtin_amdgcn_raw_buffer_load_b64)
__device__ __forceinline__ f32x2 bload2(RSRC_T r, int boff) {
    return __builtin_bit_cast(f32x2, __builtin_amdgcn_raw_buffer_load_b64(r, boff, 0, 0));
}
#else
__device__ __forceinline__ f32x2 bload2(RSRC_T r, int boff) {
    f32x2 v; v.x = bload(r, boff); v.y = bload(r, boff + 4); return v;
}
#endif

__device__ __forceinline__ float wave_reduce(float v) {
    #pragma unroll
    for (int off = 32; off > 0; off >>= 1) v += __shfl_down(v, off, 64);
    return v;
}

// Per-sample prep state: 4 row-base byte offsets + 6 final weights.
// x-edges resolved in the weights (R13-proven):
//   interior: (wa,wb)=(wx0,wx1); x0=63: (0,wx0); x0=-1: (wx1,0); else (0,0).
struct Prep {
    int o[4];
    float wa, wb, wy0, wy1, wz0, wz1;
};

// SLOW path (boundary waves): R12/R13-proven full clamp+zero prep.
// All offsets in-bounds by construction (R3/R7: never pair a possibly
// negative SRSRC voffset with a folded imm).
__device__ __forceinline__ Prep prep_s(float ix, float iy, float iz) {
    const float fx = floorf(ix), fy = floorf(iy), fz = floorf(iz);
    const int x0 = (int)fx, y0 = (int)fy, z0 = (int)fz;
    const int x1 = x0 + 1,  y1 = y0 + 1,  z1 = z0 + 1;

    const float wx1 = ix - fx, wx0 = 1.f - wx1;
    Prep p;
    p.wy1 = iy - fy; p.wy0 = 1.f - p.wy1;
    p.wz1 = iz - fz; p.wz0 = 1.f - p.wz1;
    p.wy0 = ((unsigned)y0 < 128u) ? p.wy0 : 0.f;
    p.wy1 = ((unsigned)y1 < 128u) ? p.wy1 : 0.f;
    p.wz0 = ((unsigned)z0 < 128u) ? p.wz0 : 0.f;
    p.wz1 = ((unsigned)z1 < 128u) ? p.wz1 : 0.f;

    const float wx0z = ((unsigned)x0 < 64u) ? wx0 : 0.f;
    const float wx1z = ((unsigned)x1 < 64u) ? wx1 : 0.f;
    const bool hi = (x0 >= 63);
    const bool lo = (x0 < 0);
    p.wa = lo ? wx1z : (hi ? 0.f : wx0z);
    p.wb = hi ? wx0z : (lo ? 0.f : wx1z);

    const int yc0 = min(max(y0, 0), 127), yc1 = min(max(y1, 0), 127);
    const int zc0 = min(max(z0, 0), 127), zc1 = min(max(z1, 0), 127);
    const int xpb = min(max(x0, 0), 62) << 2;
    const int yb0 = (yc0 << 8) + xpb, yb1 = (yc1 << 8) + xpb;
    const int zb0 = zc0 << 15,        zb1 = zc1 << 15;
    p.o[0] = zb0 + yb0; p.o[1] = zb0 + yb1;
    p.o[2] = zb1 + yb0; p.o[3] = zb1 + yb1;
    return p;
}

// FAST path: wave-uniformly y0,z0 in [0,126] -> rows y0,y0+1,z0,z0+1 all
// valid: no y/z zeroing, no clamps, one row base rb>=0 with folded-imm
// offsets (+256/+32768/+33024 — safe: voffset non-negative, R3/R7 rule).
// x-edge logic identical to slow path (every wave spans the full x-row).
__device__ __forceinline__ Prep prep_f(float ix, float iy, float fyf, int y0,
                                       float iz, float fzf, int z0) {
    Prep p;
    p.wy1 = iy - fyf; p.wy0 = 1.f - p.wy1;
    p.wz1 = iz - fzf; p.wz0 = 1.f - p.wz1;

    const float fx = floorf(ix);
    const int x0 = (int)fx;
    const float wx1 = ix - fx, wx0 = 1.f - wx1;
    const float wx0z = ((unsigned)x0 < 64u) ? wx0 : 0.f;
    const float wx1z = ((unsigned)(x0 + 1) < 64u) ? wx1 : 0.f;
    const bool hi = (x0 >= 63);
    const bool lo = (x0 < 0);
    p.wa = lo ? wx1z : (hi ? 0.f : wx0z);
    p.wb = hi ? wx0z : (lo ? 0.f : wx1z);

    const int rb = (z0 << 15) + (y0 << 8) + (min(max(x0, 0), 62) << 2);
    p.o[0] = rb;           p.o[1] = rb + 256;
    p.o[2] = rb + 32768;   p.o[3] = rb + 32768 + 256;
    return p;
}

__device__ __forceinline__ float blend_s(const Prep& p, const f32x2 v[4]) {
    const float bx00 = fmaf(p.wb, v[0].y, p.wa * v[0].x);
    const float bx01 = fmaf(p.wb, v[1].y, p.wa * v[1].x);
    const float bx10 = fmaf(p.wb, v[2].y, p.wa * v[2].x);
    const float bx11 = fmaf(p.wb, v[3].y, p.wa * v[3].x);
    const float by0  = fmaf(p.wy1, bx01, p.wy0 * bx00);
    const float by1  = fmaf(p.wy1, bx11, p.wy0 * bx10);
    return fmaf(p.wz1, by1, p.wz0 * by0);
}

// ---------------------------------------------------------------------------
// K1: exact R13 structure (one thread = TWO x-adjacent voxels, flat lnw load,
// NT x_reg store — R15 lesson: buffer_store loses the NT hint and thrashes
// L2 with the 32MB write stream) + the ONLY new lever this round: a wave-
// uniform y/z-interior fast-path prep.
// ---------------------------------------------------------------------------
__global__ __launch_bounds__(256) void k_sample(
    const float* __restrict__ x, const int* __restrict__ r_index,
    const float* __restrict__ theta, const float* __restrict__ lnw,
    float* __restrict__ x_reg, float* __restrict__ partial)
{
    const int b  = blockIdx.y;
    const int i2 = blockIdx.x * 256 + threadIdx.x;   // pair index
    const int w0 = (i2 & 31) << 1;                   // w of voxel 0
    const int h  = (i2 >> 5) & 127;
    const int d  = i2 >> 12;

    const f32x2 w2 = ((const f32x2*)lnw)[i2];        // issue early

    const float xs = fmaf((float)w0, 1.f/32.f, 1.f/64.f  - 1.f);
    const float ys = fmaf((float)h,  1.f/64.f, 1.f/128.f - 1.f);
    const float zs = fmaf((float)d,  1.f/64.f, 1.f/128.f - 1.f);

    const float* __restrict__ t = theta + r_index[b] * 12;   // uniform
    const float gx = fmaf(t[0], xs, fmaf(t[1], ys, fmaf(t[2],  zs, t[3])));
    const float gy = fmaf(t[4], xs, fmaf(t[5], ys, fmaf(t[6],  zs, t[7])));
    const float gz = fmaf(t[8], xs, fmaf(t[9], ys, fmaf(t[10], zs, t[11])));
    const float ix0 = fmaf(gx, 32.f, 31.5f);
    const float iy0 = fmaf(gy, 64.f, 63.5f);
    const float iz0 = fmaf(gz, 64.f, 63.5f);
    const float ix1 = ix0 + t[0];
    const float iy1 = iy0 + 2.f * t[4];
    const float iz1 = iz0 + 2.f * t[8];

    const float fy0f = floorf(iy0), fz0f = floorf(iz0);
    const float fy1f = floorf(iy1), fz1f = floorf(iz1);
    const int y00 = (int)fy0f, z00 = (int)fz0f;
    const int y10 = (int)fy1f, z10 = (int)fz1f;

    const int ok = ((unsigned)y00 <= 126u) & ((unsigned)z00 <= 126u) &
                   ((unsigned)y10 <= 126u) & ((unsigned)z10 <= 126u);

    Prep p0, p1;
    if (__all(ok)) {
        p0 = prep_f(ix0, iy0, fy0f, y00, iz0, fz0f, z00);
        p1 = prep_f(ix1, iy1, fy1f, y10, iz1, fz1f, z10);
    } else {
        p0 = prep_s(ix0, iy0, iz0);
        p1 = prep_s(ix1, iy1, iz1);
    }

    const RSRC_T r = make_rsrc(x + (size_t)b * INP);
    f32x2 v0[4], v1[4];
    #pragma unroll
    for (int j = 0; j < 4; ++j) v0[j] = bload2(r, p0.o[j]);
    #pragma unroll
    for (int j = 0; j < 4; ++j) v1[j] = bload2(r, p1.o[j]);

    const float o0 = blend_s(p0, v0);
    const float o1 = blend_s(p1, v1);

    f32x2 o; o.x = o0; o.y = o1;
    __builtin_nontemporal_store(o, (f32x2*)(x_reg + (size_t)b * INP) + i2);

    // R5-proven tail: wave shfl reduce -> LDS combine -> ONE store per block
    float acc = fmaf(o1, w2.y, o0 * w2.x);
    acc = wave_reduce(acc);
    __shared__ float sm[4];
    if ((threadIdx.x & 63) == 0) sm[threadIdx.x >> 6] = acc;
    __syncthreads();
    if (threadIdx.x == 0)
        partial[b * NBLK2 + blockIdx.x] = sm[0] + sm[1] + sm[2] + sm[3];
}

// ---------------------------------------------------------------------------
// K2 (fused reduce+outer, R13-proven): grid (128 chunks, 8 batches). Each
// block redundantly reduces its batch's 2048 partials then writes its
// 8192-float chunk of L[b] = s_b * lnw.
// ---------------------------------------------------------------------------
__global__ __launch_bounds__(256) void k_outer(
    const float* __restrict__ lnw, const float* __restrict__ partial,
    float* __restrict__ L)
{
    const int b   = blockIdx.y;
    const int tid = threadIdx.x;

    const f32x4* p4 = (const f32x4*)(partial + b * NBLK2);   // 512 f32x4
    const f32x4 a0 = p4[tid];
    const f32x4 a1 = p4[tid + 256];
    float v = (a0.x + a0.y) + (a0.z + a0.w) + (a1.x + a1.y) + (a1.z + a1.w);
    v = wave_reduce(v);
    __shared__ float sm[4];
    __shared__ float smt;
    if ((tid & 63) == 0) sm[tid >> 6] = v;
    __syncthreads();
    if (tid == 0) smt = (sm[0] + sm[1]) + (sm[2] + sm[3]);
    __syncthreads();
    const float sb = smt;

    const int base = blockIdx.x * 2048 + tid;    // f32x4 units within batch
    const f32x4* w4p = (const f32x4*)lnw;
    f32x4* L4 = (f32x4*)L + (size_t)b * (INP / 4);
    #pragma unroll
    for (int k = 0; k < 8; ++k) {
        const f32x4 w4 = w4p[base + k * 256];
        __builtin_nontemporal_store(sb * w4, L4 + base + k * 256);
    }
}

extern "C" void kernel_launch(void* const* d_in, const int* in_sizes, int n_in,
                              void* d_out, int out_size, void* d_ws, size_t ws_size,
                              hipStream_t stream) {
    const float* x       = (const float*)d_in[0];
    const int*   r_index = (const int*)d_in[1];
    const float* theta   = (const float*)d_in[2];
    const float* lnw     = (const float*)d_in[3];

    float* x_reg = (float*)d_out;
    float* L     = (float*)d_out + (size_t)NB * INP;

    float* partial = (float*)d_ws;            // 8*2048 floats = 64 KB

    dim3 grid1(NBLK2, NB);
    k_sample<<<grid1, 256, 0, stream>>>(x, r_index, theta, lnw, x_reg, partial);
    dim3 grid2(128, NB);
    k_outer<<<grid2, 256, 0, stream>>>(lnw, partial, L);
}